// Round 4
// baseline (696.899 us; speedup 1.0000x reference)
//
#include <hip/hip_runtime.h>
#include <math.h>

// NSF_CL coupling flow via bf16 MFMA. N=32768, dim=256 (half=128), hid=512, K=5.
// Round 4: 8-wave/512-thread blocks, BM=32 (LDS 64KB -> 4 waves/SIMD), c2-inner
// GEMM2 loop (w1f loads shared across both rt2 row-tiles), w1f relaid [c2][d][lane]
// for immediate-offset addressing. Numeric formulas identical to r3 (validated).

#define NROWS 32768
#define DIMX  256
#define HALF  128
#define HID   512
#define BM    32     // rows per block

typedef __attribute__((ext_vector_type(8))) short short8;   // 8 bf16 = 4 VGPR
typedef __attribute__((ext_vector_type(4))) float f32x4;

__device__ __forceinline__ unsigned short f2bf(float x) {   // RNE f32->bf16 bits
    unsigned int u = __float_as_uint(x);
    u += 0x7fffu + ((u >> 16) & 1u);
    return (unsigned short)(u >> 16);
}

__device__ __forceinline__ float frcp(float x) { return __builtin_amdgcn_rcpf(x); }

__device__ __forceinline__ float spf(float x) {             // fast softplus
    return fmaxf(x, 0.f) + __logf(1.f + __expf(-fabsf(x)));
}

// out = 1e-3 + 0.995 * softmax(6 * softmax(P))
__device__ __forceinline__ void dsm5(const float* P, float* out) {
    float e[5];
    float m = fmaxf(fmaxf(fmaxf(P[0], P[1]), fmaxf(P[2], P[3])), P[4]);
    float s = 0.f;
    #pragma unroll
    for (int p = 0; p < 5; ++p) { e[p] = __expf(P[p] - m); s += e[p]; }
    float r = 6.f * frcp(s);
    float s2 = 0.f;
    #pragma unroll
    for (int p = 0; p < 5; ++p) { e[p] = __expf(e[p] * r); s2 += e[p]; }
    float r2 = 0.995f * frcp(s2);
    #pragma unroll
    for (int p = 0; p < 5; ++p) out[p] = 1.0e-3f + e[p] * r2;
}

// P[0..4]=W raw, P[5..9]=H raw, P[10..13]=D raw. Fused cumsum + bucket select.
__device__ __forceinline__ void rqs_fast(const float* P, float xa, float& yo, float& ldo) {
    float wv[5], hv[5];
    dsm5(P, wv);
    dsm5(P + 5, hv);
    float dvi[4];
    #pragma unroll
    for (int p = 0; p < 4; ++p) dvi[p] = 1.0e-3f + spf(spf(P[10 + p]));
    float xc = fminf(fmaxf(xa, -3.f), 3.f);
    float csw = wv[0], csh = hv[0];
    float in_cw = -3.f, in_ch = -3.f;
    float in_w = 6.f * csw, in_h = 6.f * csh;
    float dk = 1.f, dk1 = dvi[0];
    #pragma unroll
    for (int p = 1; p < 5; ++p) {
        float cwp = 6.f * csw - 3.f;
        float chp = 6.f * csh - 3.f;
        csw += wv[p]; csh += hv[p];
        float cwp1 = (p == 4) ? 3.f : (6.f * csw - 3.f);
        float chp1 = (p == 4) ? 3.f : (6.f * csh - 3.f);
        bool take = (xc >= cwp);
        in_cw = take ? cwp : in_cw;
        in_w  = take ? (cwp1 - cwp) : in_w;
        in_ch = take ? chp : in_ch;
        in_h  = take ? (chp1 - chp) : in_h;
        dk    = take ? dvi[p - 1] : dk;
        dk1   = take ? ((p == 4) ? 1.f : dvi[p]) : dk1;
    }
    float rw = frcp(in_w);
    float th = (xc - in_cw) * rw;
    float om = 1.f - th;
    float t1m = th * om;
    float delta = in_h * rw;
    float num = in_h * (delta * th * th + dk * t1m);
    float den = delta + (dk + dk1 - 2.f * delta) * t1m;
    float y = in_ch + num * frcp(den);
    float dnum = delta * delta * (dk1 * th * th + 2.f * delta * t1m + dk * om * om);
    float ld = __logf(dnum) - 2.f * __logf(den);
    bool inside = (xa >= -3.f) && (xa <= 3.f);
    yo  = inside ? y : xa;
    ldo = inside ? ld : 0.f;
}

// ---------- prep: weights -> bf16 fragment order ----------
// w1f[stage][c2 16][d 128][lane 64] = ushort8: e -> w1[k=32*c2+8*(l>>4)+e][d*14+(l&15)] (0 if p>=14)
// w0f[stage][ct 32][c 4][lane 64]   = ushort8: e -> w0[k=32*c +8*(l>>4)+e][ct*16+(l&15)]
// b1p[stage][d 128][16]             = b1[d*14+p] (0 if p>=14)
__global__ void prep(const float* __restrict__ w1a, const float* __restrict__ w1b,
                     const float* __restrict__ w0a, const float* __restrict__ w0b,
                     const float* __restrict__ b1a, const float* __restrict__ b1b,
                     short* __restrict__ w1f, short* __restrict__ w0f, float* __restrict__ b1p) {
    int idx = blockIdx.x * 256 + threadIdx.x;
    if (idx < 262144) {
        int stage = idx >> 17, rem = idx & 131071;
        int c2 = rem >> 13, d = (rem >> 6) & 127, l = rem & 63;
        const float* src = stage ? w1b : w1a;
        int p = l & 15, g = l >> 4;
        short8 o;
        #pragma unroll
        for (int e = 0; e < 8; ++e) {
            int k = 32 * c2 + 8 * g + e;
            float v = (p < 14) ? src[(size_t)k * 1792 + d * 14 + p] : 0.f;
            o[e] = (short)f2bf(v);
        }
        *reinterpret_cast<short8*>(w1f + (size_t)stage * 1048576 + (size_t)rem * 8) = o;
    } else if (idx < 278528) {
        int r = idx - 262144;
        int stage = r >> 13, rem = r & 8191;
        int l = rem & 63;
        const float* src = stage ? w0b : w0a;
        int p = l & 15, g = l >> 4;
        int ct = rem >> 8, c = (rem >> 6) & 3;
        short8 o;
        #pragma unroll
        for (int e = 0; e < 8; ++e) {
            int k = 32 * c + 8 * g + e;
            o[e] = (short)f2bf(src[k * 512 + ct * 16 + p]);
        }
        *reinterpret_cast<short8*>(w0f + stage * 65536 + rem * 8) = o;
    } else if (idx < 282624) {
        int r = idx - 278528;
        int stage = r >> 11, rem = r & 2047;
        int d = rem >> 4, p = rem & 15;
        const float* src = stage ? b1b : b1a;
        b1p[stage * 2048 + rem] = (p < 14) ? src[d * 14 + p] : 0.f;
    }
}

// ---------- fused stage kernel: 8 waves, 32 rows/block ----------
template <int STAGE>
__global__ __launch_bounds__(512, 4)
void nsf_stage(const float* __restrict__ xin, float* __restrict__ zout,
               float* __restrict__ ld_out,
               const short* __restrict__ w0f, const float* __restrict__ b0,
               const short* __restrict__ w1f, const float* __restrict__ b1p) {
    __shared__ __align__(16) short hA2[16384];   // 32 KB: [rt2 2][c2 16][lane 64][e 8] bf16
    __shared__ __align__(16) float pbuf[8192];   // 32 KB: per-wave 1024 f32; A1 alias in phase 0/1
    short* A1 = reinterpret_cast<short*>(pbuf);  // 8 frags x 64 lanes x 8 bf16 = 8 KB

    const int tid = threadIdx.x;
    const int lane = tid & 63;
    const int w = tid >> 6;                      // 8 waves
    const int n0 = blockIdx.x * BM;

    const float* cond = STAGE ? zout : xin;
    const int coff = STAGE ? HALF : 0;
    const int aoff = STAGE ? 0 : HALF;
    const int yoff = STAGE ? 0 : HALF;

    // ---- phase 0: cond tile [32][128] -> bf16 A1 fragments (512 threads, 1 frag-slot each)
    {
        int fr = tid >> 6, l = tid & 63;
        int rt = fr >> 2, c = fr & 3;
        int row = rt * 16 + (l & 15);
        int kb = 32 * c + 8 * (l >> 4);
        const float* sp = cond + (size_t)(n0 + row) * DIMX + coff + kb;
        short8 o;
        #pragma unroll
        for (int e = 0; e < 8; ++e) o[e] = (short)f2bf(sp[e]);
        *reinterpret_cast<short8*>(A1 + tid * 8) = o;
    }
    __syncthreads();

    // ---- phase 1: h = tanh(cond @ w0 + b0) -> bf16 A2-frag order (8 waves x 4 ct each)
    for (int rt = 0; rt < 2; ++rt) {
        short8 a1[4];
        #pragma unroll
        for (int c = 0; c < 4; ++c)
            a1[c] = *reinterpret_cast<const short8*>(A1 + ((rt * 4 + c) * 64 + lane) * 8);
        #pragma unroll
        for (int j = 0; j < 4; ++j) {
            int ct = w * 4 + j;
            f32x4 acc = {0.f, 0.f, 0.f, 0.f};
            #pragma unroll
            for (int c = 0; c < 4; ++c) {
                short8 b = *reinterpret_cast<const short8*>(w0f + ((ct * 4 + c) * 64 + lane) * 8);
                acc = __builtin_amdgcn_mfma_f32_16x16x32_bf16(a1[c], b, acc, 0, 0, 0);
            }
            float bv = b0[ct * 16 + (lane & 15)];
            int q = (2 * ct + ((lane & 15) >> 3)) & 3;
            int c2 = ct >> 1;
            #pragma unroll
            for (int r = 0; r < 4; ++r) {
                float av = acc[r] + bv;
                float e2 = __expf(2.f * av);
                float hvf = 1.f - 2.f * frcp(e2 + 1.f);
                int i = (lane >> 4) * 4 + r;
                hA2[((rt * 16 + c2) * 64 + (i + 16 * q)) * 8 + (lane & 7)] = (short)f2bf(hvf);
            }
        }
    }
    __syncthreads();

    // ---- phase 2: per dg (4 d-cols), K-loop c2-inner; w1f load shared by both rt2
    float ldp[2] = {0.f, 0.f};
    float* pb = pbuf + w * 1024;                 // wave-private transpose buffer
    for (int dg = 0; dg < 4; ++dg) {
        const int d0 = w * 16 + dg * 4;          // wave's 16-d slice, 4 at a time
        f32x4 acc[2][4];
        #pragma unroll
        for (int q = 0; q < 2; ++q)
            #pragma unroll
            for (int dd = 0; dd < 4; ++dd) acc[q][dd] = (f32x4){0.f, 0.f, 0.f, 0.f};
        #pragma unroll
        for (int c2 = 0; c2 < 16; ++c2) {
            short8 a20 = *reinterpret_cast<const short8*>(hA2 + (c2 * 64 + lane) * 8);
            short8 a21 = *reinterpret_cast<const short8*>(hA2 + ((16 + c2) * 64 + lane) * 8);
            #pragma unroll
            for (int dd = 0; dd < 4; ++dd) {
                short8 b = *reinterpret_cast<const short8*>(
                    w1f + ((size_t)(c2 * 128 + d0 + dd) * 64 + lane) * 8);
                acc[0][dd] = __builtin_amdgcn_mfma_f32_16x16x32_bf16(a20, b, acc[0][dd], 0, 0, 0);
                acc[1][dd] = __builtin_amdgcn_mfma_f32_16x16x32_bf16(a21, b, acc[1][dd], 0, 0, 0);
            }
        }
        float bvv[4];
        #pragma unroll
        for (int dd = 0; dd < 4; ++dd) bvv[dd] = b1p[(d0 + dd) * 16 + (lane & 15)];
        #pragma unroll
        for (int rt2 = 0; rt2 < 2; ++rt2) {
            // bias + XOR-swizzled transpose through wave-private LDS
            #pragma unroll
            for (int dd = 0; dd < 4; ++dd) {
                #pragma unroll
                for (int r = 0; r < 4; ++r) {
                    int rl = (lane >> 4) * 4 + r;
                    pb[dd * 256 + rl * 16 + ((lane & 15) ^ (((rl >> 1) & 3) << 2))] =
                        acc[rt2][dd][r] + bvv[dd];
                }
            }
            asm volatile("s_waitcnt lgkmcnt(0)" ::: "memory");
            __builtin_amdgcn_sched_barrier(0);
            // spline: lane -> (row = lane&15, d = d0 + lane>>4)
            {
                int rl = lane & 15, dd = lane >> 4;
                int s = ((rl >> 1) & 3) << 2;
                const float* rb = pb + dd * 256 + rl * 16;
                float P[16];
                #pragma unroll
                for (int qd = 0; qd < 4; ++qd) {
                    f32x4 v = *reinterpret_cast<const f32x4*>(rb + ((qd * 4) ^ s));
                    P[qd * 4 + 0] = v[0]; P[qd * 4 + 1] = v[1];
                    P[qd * 4 + 2] = v[2]; P[qd * 4 + 3] = v[3];
                }
                size_t nrow = (size_t)(n0 + rt2 * 16 + rl) * DIMX;
                float xa = xin[nrow + aoff + d0 + dd];
                float y, ldv;
                rqs_fast(P, xa, y, ldv);
                zout[nrow + yoff + d0 + dd] = y;
                ldv += __shfl_xor(ldv, 16, 64);
                ldv += __shfl_xor(ldv, 32, 64);
                ldp[rt2] += ldv;      // lanes 0..15 carry the canonical row sums
            }
        }
    }

    // ---- log-det: per-wave partials (16-d slice each) -> LDS -> block reduce
    if (lane < 16) {
        pb[lane] = ldp[0];
        pb[16 + lane] = ldp[1];
    }
    __syncthreads();
    if (tid < BM) {
        float s = 0.f;
        #pragma unroll
        for (int ww = 0; ww < 8; ++ww) s += pbuf[ww * 1024 + tid];
        if (STAGE == 0) ld_out[n0 + tid] = s;
        else            ld_out[n0 + tid] += s;
    }
}

// ---------- launch ----------
extern "C" void kernel_launch(void* const* d_in, const int* in_sizes, int n_in,
                              void* d_out, int out_size, void* d_ws, size_t ws_size,
                              hipStream_t stream) {
    const float* x     = (const float*)d_in[0];
    const float* f0_w0 = (const float*)d_in[1];
    const float* f0_b0 = (const float*)d_in[2];
    const float* f0_w1 = (const float*)d_in[3];
    const float* f0_b1 = (const float*)d_in[4];
    const float* f1_w0 = (const float*)d_in[5];
    const float* f1_b0 = (const float*)d_in[6];
    const float* f1_w1 = (const float*)d_in[7];
    const float* f1_b1 = (const float*)d_in[8];

    float* zout = (float*)d_out;
    float* ld   = zout + (size_t)NROWS * DIMX;

    short* w1f = (short*)d_ws;                                     // 2 x 2 MB
    short* w0f = (short*)((char*)d_ws + 4 * 1024 * 1024);          // 2 x 128 KB
    float* b1p = (float*)((char*)d_ws + 4 * 1024 * 1024 + 256 * 1024); // 2 x 8 KB

    prep<<<1104, 256, 0, stream>>>(f0_w1, f1_w1, f0_w0, f1_w0, f0_b1, f1_b1, w1f, w0f, b1p);
    nsf_stage<0><<<NROWS / BM, 512, 0, stream>>>(x, zout, ld, w0f, f0_b0, w1f, b1p);
    nsf_stage<1><<<NROWS / BM, 512, 0, stream>>>(x, zout, ld, w0f + 65536, f1_b0,
                                                 w1f + 1048576, b1p + 2048);
}